// Round 3
// baseline (89.901 us; speedup 1.0000x reference)
//
#include <hip/hip_runtime.h>

typedef float f32x4 __attribute__((ext_vector_type(4)));
typedef short bf16x8 __attribute__((ext_vector_type(8)));

__device__ __forceinline__ short f2bf(float x) {
    unsigned u = __float_as_uint(x);
    unsigned r = (u + 0x7FFFu + ((u >> 16) & 1u)) >> 16;  // RNE
    return (short)r;
}

// ---------------- prep 1: An2 = (D^-1/2 (W+I) D^-1/2)^2, written as bf16 A-fragments ----------------
__global__ void prep_an2(const float* __restrict__ tril, short* __restrict__ an2f) {
    __shared__ float Wm[64][64];
    __shared__ float An[64][64];
    __shared__ float An2[64][64];
    __shared__ float dinv[64];
    const int t = threadIdx.x;  // 256 threads
    for (int e = t; e < 4096; e += 256) {
        int i = e >> 6, j = e & 63;
        int hi = i > j ? i : j, lo = i > j ? j : i;
        Wm[i][j] = tril[hi * (hi + 1) / 2 + lo];  // symmetric rebuild
    }
    __syncthreads();
    if (t < 64) {
        float s = 0.f;
        for (int j = 0; j < 64; ++j) s += fabsf(Wm[t][j]);
        s += 1.0f;
        dinv[t] = (s > 0.f) ? 1.0f / sqrtf(s) : 0.f;
    }
    __syncthreads();
    for (int e = t; e < 4096; e += 256) {
        int i = e >> 6, j = e & 63;
        float a = Wm[i][j] + (i == j ? 1.0f : 0.0f);
        An[i][j] = dinv[i] * a * dinv[j];
    }
    __syncthreads();
    for (int e = t; e < 4096; e += 256) {
        int i = e >> 6, j = e & 63;
        float acc = 0.f;
        for (int m = 0; m < 64; ++m) acc += An[i][m] * An[m][j];
        An2[i][j] = acc;
    }
    __syncthreads();
    // A-fragment order: [mt(4)][kt(2)][lane(64)][e(8)], elem = An2[mt*16+(lane&15)][kt*32+8*(lane>>4)+e]
    for (int o = t; o < 4096; o += 256) {
        int e = o & 7, lane = (o >> 3) & 63, kt = (o >> 9) & 1, mt = o >> 10;
        int m = mt * 16 + (lane & 15);
        int k = kt * 32 + 8 * (lane >> 4) + e;
        an2f[o] = f2bf(An2[m][k]);
    }
}

// ---------------- prep 2: convW -> bf16 B-fragments [kt(8)][nt(32)][lane(64)][e(8)] ----------------
__global__ void prep_wf(const float* __restrict__ convW, short* __restrict__ wf) {
    int o = blockIdx.x * 256 + threadIdx.x;  // 131072 elements
    int e = o & 7, lane = (o >> 3) & 63, nt = (o >> 9) & 31, kt = o >> 14;
    int k = kt * 32 + 8 * (lane >> 4) + e;
    int j = nt * 16 + (lane & 15);
    wf[o] = f2bf(convW[k * 512 + j]);
}

// ---------------- main: per-batch fused hop+conv+pool+fc+log_softmax ----------------
__global__ __launch_bounds__(256, 2) void rgnn_main(
    const float* __restrict__ X, const short* __restrict__ an2f,
    const short* __restrict__ wf, const float* __restrict__ convb,
    const float* __restrict__ fcW, const float* __restrict__ fcb,
    float* __restrict__ out)
{
    __shared__ short xbt[256 * 64];  // X[b]^T as [c][m], bf16, XOR-swizzled rows (128B stride)
    __shared__ short xs[64 * 256];   // x = An2@X[b] as [n][c], bf16, XOR-swizzled rows (512B stride)
    __shared__ float pooled[512];
    const int b = blockIdx.x;
    const int t = threadIdx.x;
    const int lane = t & 63;
    const int wid = t >> 6;
    const float* Xb = X + (size_t)b * (64 * 256);

    // ---- stage X[b] -> xbt (bf16, transposed, swizzled). Reads coalesced 256B/wave-instr.
    {
        const int c = t;  // feature column 0..255
        #pragma unroll
        for (int m0 = 0; m0 < 64; m0 += 8) {
            bf16x8 v;
            #pragma unroll
            for (int i = 0; i < 8; ++i) v[i] = f2bf(Xb[(m0 + i) * 256 + c]);
            int byte = c * 128 + m0 * 2;
            byte ^= (c & 7) << 4;
            *(bf16x8*)((char*)xbt + byte) = v;
        }
    }
    __syncthreads();

    // ---- phase A: x = An2 @ X[b].  A=An2 frags (global), B=xbt (LDS). Wave: c-slice of 64.
    {
        const int c0 = wid * 64;
        f32x4 acc[4][4];
        #pragma unroll
        for (int mt = 0; mt < 4; ++mt)
            #pragma unroll
            for (int nt = 0; nt < 4; ++nt) acc[mt][nt] = (f32x4)0.f;
        bf16x8 afr[4][2];
        #pragma unroll
        for (int mt = 0; mt < 4; ++mt)
            #pragma unroll
            for (int kt = 0; kt < 2; ++kt)
                afr[mt][kt] = *(const bf16x8*)&an2f[((mt * 2 + kt) * 64 + lane) * 8];
        #pragma unroll
        for (int kt = 0; kt < 2; ++kt) {
            #pragma unroll
            for (int nt = 0; nt < 4; ++nt) {
                int row = c0 + nt * 16 + (lane & 15);
                int byte = row * 128 + (kt * 32 + 8 * (lane >> 4)) * 2;
                byte ^= (row & 7) << 4;
                bf16x8 bfr = *(const bf16x8*)((const char*)xbt + byte);
                #pragma unroll
                for (int mt = 0; mt < 4; ++mt)
                    acc[mt][nt] = __builtin_amdgcn_mfma_f32_16x16x32_bf16(afr[mt][kt], bfr, acc[mt][nt], 0, 0, 0);
            }
        }
        // C layout (verified): col = lane&15, row = (lane>>4)*4 + r. Write x[row][col] bf16 swizzled.
        #pragma unroll
        for (int mt = 0; mt < 4; ++mt)
            #pragma unroll
            for (int nt = 0; nt < 4; ++nt)
                #pragma unroll
                for (int r = 0; r < 4; ++r) {
                    int row = mt * 16 + (lane >> 4) * 4 + r;
                    int col = c0 + nt * 16 + (lane & 15);
                    int byte = row * 512 + col * 2;
                    byte ^= (row & 7) << 4;
                    *(short*)((char*)xs + byte) = f2bf(acc[mt][nt][r]);
                }
    }
    __syncthreads();

    // ---- phase B: pooled = sum_n relu(x @ convW + b). Wave: j-slice of 128.
    {
        const int j0 = wid * 128;
        f32x4 acc[4][8];
        #pragma unroll
        for (int mt = 0; mt < 4; ++mt)
            #pragma unroll
            for (int nt = 0; nt < 8; ++nt) acc[mt][nt] = (f32x4)0.f;
        #pragma unroll
        for (int kt = 0; kt < 8; ++kt) {
            bf16x8 bfr[8];
            #pragma unroll
            for (int nt = 0; nt < 8; ++nt) {
                int ntg = (j0 >> 4) + nt;
                bfr[nt] = *(const bf16x8*)&wf[((kt * 32 + ntg) * 64 + lane) * 8];
            }
            #pragma unroll
            for (int mt = 0; mt < 4; ++mt) {
                int row = mt * 16 + (lane & 15);
                int byte = row * 512 + (kt * 32 + 8 * (lane >> 4)) * 2;
                byte ^= (row & 7) << 4;
                bf16x8 afr = *(const bf16x8*)((const char*)xs + byte);
                #pragma unroll
                for (int nt = 0; nt < 8; ++nt)
                    acc[mt][nt] = __builtin_amdgcn_mfma_f32_16x16x32_bf16(afr, bfr[nt], acc[mt][nt], 0, 0, 0);
            }
        }
        // bias + relu + pool over nodes (rows). Lane groups (lane>>4) hold different rows of same col.
        #pragma unroll
        for (int nt = 0; nt < 8; ++nt) {
            int j = j0 + nt * 16 + (lane & 15);
            float bj = convb[j];
            float s = 0.f;
            #pragma unroll
            for (int mt = 0; mt < 4; ++mt)
                #pragma unroll
                for (int r = 0; r < 4; ++r)
                    s += fmaxf(acc[mt][nt][r] + bj, 0.f);
            s += __shfl_xor(s, 16);
            s += __shfl_xor(s, 32);
            if (lane < 16) pooled[j] = s;
        }
    }
    __syncthreads();

    // ---- fc (512 -> 2) + log_softmax, one wave
    if (wid == 0) {
        float p0 = 0.f, p1 = 0.f;
        #pragma unroll
        for (int j = lane; j < 512; j += 64) {
            float pv = pooled[j];
            p0 += pv * fcW[j];
            p1 += pv * fcW[512 + j];
        }
        #pragma unroll
        for (int d = 1; d < 64; d <<= 1) {
            p0 += __shfl_xor(p0, d);
            p1 += __shfl_xor(p1, d);
        }
        if (lane == 0) {
            float l0 = p0 + fcb[0], l1 = p1 + fcb[1];
            float m = fmaxf(l0, l1);
            float lse = m + logf(expf(l0 - m) + expf(l1 - m));
            out[b * 2 + 0] = l0 - lse;
            out[b * 2 + 1] = l1 - lse;
        }
    }
}

extern "C" void kernel_launch(void* const* d_in, const int* in_sizes, int n_in,
                              void* d_out, int out_size, void* d_ws, size_t ws_size,
                              hipStream_t stream) {
    const float* X     = (const float*)d_in[0];
    const float* tril  = (const float*)d_in[1];
    const float* convW = (const float*)d_in[2];
    const float* convb = (const float*)d_in[3];
    const float* fcW   = (const float*)d_in[4];
    const float* fcb   = (const float*)d_in[5];
    float* out = (float*)d_out;
    short* an2f = (short*)d_ws;          // 4096 bf16 = 8KB
    short* wf   = an2f + 4096;           // 131072 bf16 = 256KB
    prep_an2<<<dim3(1), dim3(256), 0, stream>>>(tril, an2f);
    prep_wf<<<dim3(512), dim3(256), 0, stream>>>(convW, wf);
    rgnn_main<<<dim3(2048), dim3(256), 0, stream>>>(X, an2f, wf, convb, fcW, fcb, out);
}